// Round 5
// baseline (354.162 us; speedup 1.0000x reference)
//
#include <hip/hip_runtime.h>
#include <stdint.h>

typedef unsigned short u16;
typedef __bf16 bf16x8 __attribute__((ext_vector_type(8)));
typedef short s4 __attribute__((ext_vector_type(4)));
typedef float f32x4 __attribute__((ext_vector_type(4)));

#define B_ 2
#define S_ 2048
#define H_ 2048
#define NH_ 16
#define HD_ 128

// softmax scale folded with log2(e): exp(s*scale) == exp2(s*SL2)
#define SL2f (0.08838834764831845f * 1.4426950408889634f)

__device__ __forceinline__ u16 f2bf(float f) {
    uint32_t u = __float_as_uint(f);
    u += 0x7fff + ((u >> 16) & 1);  // round-to-nearest-even
    return (u16)(u >> 16);
}

// pack two f32 -> two bf16 (truncation) in ONE v_perm_b32
__device__ __forceinline__ uint32_t pk_bf16(float lo, float hi) {
    return __builtin_amdgcn_perm(__float_as_uint(hi), __float_as_uint(lo), 0x07060302u);
}

// async global->LDS, 16B per lane, LDS dest = wave-uniform base + lane*16
__device__ __forceinline__ void gl_lds16(const u16* g, u16* l) {
    __builtin_amdgcn_global_load_lds(
        (const __attribute__((address_space(1))) void*)g,
        (__attribute__((address_space(3))) void*)l, 16, 0, 0);
}

union U2S4 { uint2 u; s4 s; };

// ---------------- cast x (fp32 -> bf16) ----------------
__global__ __launch_bounds__(256) void cast_x_kernel(const float* __restrict__ x, u16* __restrict__ xb) {
    int i = (blockIdx.x * 256 + threadIdx.x) * 4;
    float4 v = *(const float4*)&x[i];
    ushort4 o;
    o.x = f2bf(v.x); o.y = f2bf(v.y); o.z = f2bf(v.z); o.w = f2bf(v.w);
    *(ushort4*)&xb[i] = o;
}

// ---------------- transpose + cast weights: Wt[n][k] = bf16(W[k][n]) ----------------
__global__ __launch_bounds__(256) void transpose_cast_kernel(
        const float* __restrict__ w0, const float* __restrict__ w1,
        const float* __restrict__ w2, const float* __restrict__ w3,
        u16* __restrict__ dqkv, u16* __restrict__ dwo) {
    int z = blockIdx.z;
    const float* src = (z == 0) ? w0 : (z == 1) ? w1 : (z == 2) ? w2 : w3;
    u16* dst = (z < 3) ? (dqkv + (size_t)z * H_ * H_) : dwo;
    __shared__ float tile[32][33];
    int n0 = blockIdx.x * 32, k0 = blockIdx.y * 32;
    int tx = threadIdx.x, ty = threadIdx.y;  // 32 x 8
#pragma unroll
    for (int i = 0; i < 4; i++)
        tile[ty + i * 8][tx] = src[(size_t)(k0 + ty + i * 8) * H_ + n0 + tx];
    __syncthreads();
#pragma unroll
    for (int i = 0; i < 4; i++)
        dst[(size_t)(n0 + ty + i * 8) * H_ + k0 + tx] = f2bf(tile[tx][ty + i * 8]);
}

// ---------------- GEMM: C[M,N] = A[M,K] @ Bt[N,K]^T  (bf16 in, fp32 acc) ----------------
// MODE 0: N=6144 (Q|K|V). Q pre-scaled by SL2f -> Qb[b,h,s,d]; K -> Kbuf[b,h,s,d];
//         V-tiles transposed through LDS -> VT[b,h,d,s] with coalesced b128 stores.
// MODE 1: fp32 row-major output [M,N].
template <int MODE>
__global__ __launch_bounds__(256, 2) void gemm_bt(
        const u16* __restrict__ A, const u16* __restrict__ Bt, float* __restrict__ Cout,
        u16* __restrict__ q, u16* __restrict__ k, u16* __restrict__ v,
        int M, int N, int K) {
    __shared__ u16 sm[2 * 128 * 64];   // As | Bs; reused as 128x128 u16 for V epilogue
    u16* As = sm;
    u16* Bs = sm + 128 * 64;
    int tid = threadIdx.x;
    int w = tid >> 6, lane = tid & 63, quad = lane >> 4, l16 = lane & 15;
    int wm = w >> 1, wn = w & 1;
    int m0 = blockIdx.y * 128, n0 = blockIdx.x * 128;

    f32x4 acc[4][4];
#pragma unroll
    for (int mi = 0; mi < 4; mi++)
#pragma unroll
        for (int ni = 0; ni < 4; ni++)
            acc[mi][ni] = (f32x4){0.f, 0.f, 0.f, 0.f};

    for (int k0 = 0; k0 < K; k0 += 64) {
        const u16* ga = A + (size_t)m0 * K + k0;
        const u16* gb = Bt + (size_t)n0 * K + k0;
#pragma unroll
        for (int j = 0; j < 4; j++) {
            int base = (j * 4 + w) * 64;
            int p = base + lane;
            int row = p >> 3;
            int c = (p & 7) ^ (row & 7);
            gl_lds16(&ga[(size_t)row * K + c * 8], &As[base * 8]);
            gl_lds16(&gb[(size_t)row * K + c * 8], &Bs[base * 8]);
        }
        __syncthreads();
#pragma unroll
        for (int ks = 0; ks < 2; ks++) {
            bf16x8 af[4], bf[4];
#pragma unroll
            for (int mi = 0; mi < 4; mi++) {
                int row = wm * 64 + mi * 16 + l16;
                af[mi] = *(const bf16x8*)&As[row * 64 + (((ks * 4 + quad) ^ (row & 7)) * 8)];
            }
#pragma unroll
            for (int ni = 0; ni < 4; ni++) {
                int row = wn * 64 + ni * 16 + l16;
                bf[ni] = *(const bf16x8*)&Bs[row * 64 + (((ks * 4 + quad) ^ (row & 7)) * 8)];
            }
#pragma unroll
            for (int mi = 0; mi < 4; mi++)
#pragma unroll
                for (int ni = 0; ni < 4; ni++)
                    acc[mi][ni] = __builtin_amdgcn_mfma_f32_16x16x32_bf16(af[mi], bf[ni], acc[mi][ni], 0, 0, 0);
        }
        __syncthreads();
    }

    // epilogue: D layout col = lane&15, row = quad*4 + r (m89-verified)
    if (MODE == 0 && n0 >= 4096) {
        // ---- V tile: bounce through LDS (swizzled) and store VT[b,h,d,s] coalesced ----
#pragma unroll
        for (int mi = 0; mi < 4; mi++) {
#pragma unroll
            for (int ni = 0; ni < 4; ni++) {
                int nl = wn * 64 + ni * 16 + l16;
#pragma unroll
                for (int r = 0; r < 4; r++) {
                    int ml = wm * 64 + mi * 16 + quad * 4 + r;
                    sm[nl * 128 + (((ml >> 3) ^ (nl & 15)) * 8) + (ml & 7)] = f2bf(acc[mi][ni][r]);
                }
            }
        }
        __syncthreads();
        int b = m0 >> 11, s0 = m0 & 2047;
#pragma unroll
        for (int i = 0; i < 8; i++) {
            int cu = tid + i * 256;
            int nl = cu >> 4, mc = cu & 15;
            int4 val = *(const int4*)&sm[nl * 128 + ((mc ^ (nl & 15)) * 8)];
            int ngl = (n0 - 4096) + nl;
            int h = ngl >> 7, d = ngl & 127;
            *(int4*)&v[((size_t)((b * NH_ + h) * HD_ + d)) * S_ + s0 + mc * 8] = val;
        }
    } else {
#pragma unroll
        for (int mi = 0; mi < 4; mi++) {
#pragma unroll
            for (int ni = 0; ni < 4; ni++) {
                int ng = n0 + wn * 64 + ni * 16 + l16;
#pragma unroll
                for (int r = 0; r < 4; r++) {
                    int mg = m0 + wm * 64 + mi * 16 + quad * 4 + r;
                    float val = acc[mi][ni][r];
                    if (MODE == 0) {
                        int which = ng >> 11;          // 0=Q 1=K
                        int rem = ng & 2047;
                        int h = rem >> 7, d = rem & 127;
                        int b = mg >> 11, s = mg & 2047;
                        if (which == 0)
                            q[((size_t)((b * NH_ + h) * S_ + s)) * HD_ + d] = f2bf(val * SL2f);
                        else
                            k[((size_t)((b * NH_ + h) * S_ + s)) * HD_ + d] = f2bf(val);
                    } else {
                        Cout[(size_t)mg * N + ng] = val;
                    }
                }
            }
        }
    }
}

// ---------------- causal flash attention: S^T trick, P stays in registers ----------------
// 1024 blocks, longest-first (LPT). Block = 4 waves x 16 q-rows = one 64-row q-tile.
// LDS: Ks 2x16KB (dbuf DMA) + Vs 16KB (DMA from VT) = 48KB -> 3 blocks/CU.
// S^T = K·Q^T (16x16x32); C-layout == B-operand layout of 16x16x16 MFMA -> PV direct
// from registers (O^T = V^T · P^T). Q pre-scaled by SL2f.
__global__ __launch_bounds__(256, 3) void flash_kernel(
        const u16* __restrict__ Q, const u16* __restrict__ Kb,
        const u16* __restrict__ VT, u16* __restrict__ Ctx) {
    __shared__ u16 Ks[2][64 * 128];  // [kv][d], chunk c at c ^ (kv&15)
    __shared__ u16 Vs[128 * 64];     // [d][kv], chunk c at c ^ (d&7)
    int tid = threadIdx.x;
    int w = tid >> 6, lane = tid & 63, quad = lane >> 4, l16 = lane & 15;

    int id = blockIdx.x;
    int bh = id & 31;
    int b = bh >> 4, h = bh & 15;
    int qt = 31 - (id >> 5);         // longest blocks launch first (LPT packing)
    int q0 = qt * 64;

    size_t bhoff = ((size_t)b * NH_ + h) * S_ * HD_;
    const u16* Qp = Q + bhoff;
    const u16* Kp = Kb + bhoff;
    const u16* Vp = VT + bhoff;      // [d][s]

    auto stageK = [&](int t, int buf) {
        int kv0 = t * 64;
#pragma unroll
        for (int j = 0; j < 4; j++) {
            int base = (j * 4 + w) * 64;
            int p = base + lane;
            int row = p >> 4;
            int c = (p & 15) ^ (row & 15);
            gl_lds16(&Kp[(size_t)(kv0 + row) * HD_ + c * 8], &Ks[buf][base * 8]);
        }
    };
    auto stageV = [&](int t) {
        int kv0 = t * 64;
#pragma unroll
        for (int j = 0; j < 4; j++) {
            int base = (j * 4 + w) * 64;
            int p = base + lane;
            int row = p >> 3;
            int c = (p & 7) ^ (row & 7);
            gl_lds16(&Vp[(size_t)row * S_ + kv0 + c * 8], &Vs[base * 8]);
        }
    };

    int qw = q0 + w * 16;
    int qg = qw + l16;               // this lane's q row (S^T: lane = q column)
    // Q fragments (per-lane content identical for A- and B-operand semantics)
    bf16x8 qf[4];
#pragma unroll
    for (int ks = 0; ks < 4; ks++)
        qf[ks] = *(const bf16x8*)&Qp[(size_t)qg * HD_ + ks * 32 + quad * 8];

    float l_part = 0.f;
    f32x4 ao[8];                     // O^T accumulators: [d-tile], rows=d quad*4+r, col=q=l16
#pragma unroll
    for (int dt = 0; dt < 8; dt++) ao[dt] = (f32x4){0.f, 0.f, 0.f, 0.f};

    stageK(0, 0);

    for (int t = 0; t <= qt; t++) {
        int buf = t & 1;
        __syncthreads();                     // K(t) drained; Vs free
        if (t < qt) stageK(t + 1, (t + 1) & 1);
        stageV(t);

        // --- S^T = K·Q^T : 4 kv-tiles x 4 k-steps ---
        f32x4 sc[4];
#pragma unroll
        for (int nt = 0; nt < 4; nt++) {
            sc[nt] = (f32x4){0.f, 0.f, 0.f, 0.f};
            int row = nt * 16 + l16;
#pragma unroll
            for (int ks = 0; ks < 4; ks++) {
                bf16x8 kf = *(const bf16x8*)&Ks[buf][row * 128 + (((ks * 4 + quad) ^ (row & 15)) * 8)];
                sc[nt] = __builtin_amdgcn_mfma_f32_16x16x32_bf16(kf, qf[ks], sc[nt], 0, 0, 0);
            }
        }

        // --- softmax in registers; pack P^T as 16x16x16 B-fragments ---
        U2S4 pk[4];
        if (t < qt) {
#pragma unroll
            for (int nt = 0; nt < 4; nt++) {
                float p0 = exp2f(sc[nt][0]), p1 = exp2f(sc[nt][1]);
                float p2 = exp2f(sc[nt][2]), p3 = exp2f(sc[nt][3]);
                l_part += (p0 + p1) + (p2 + p3);
                pk[nt].u.x = pk_bf16(p0, p1);
                pk[nt].u.y = pk_bf16(p2, p3);
            }
        } else {                              // diagonal tile: causal mask
            int kvb = t * 64 + quad * 4;
#pragma unroll
            for (int nt = 0; nt < 4; nt++) {
                int kv = kvb + nt * 16;
                float p0 = (kv + 0 > qg) ? 0.f : exp2f(sc[nt][0]);
                float p1 = (kv + 1 > qg) ? 0.f : exp2f(sc[nt][1]);
                float p2 = (kv + 2 > qg) ? 0.f : exp2f(sc[nt][2]);
                float p3 = (kv + 3 > qg) ? 0.f : exp2f(sc[nt][3]);
                l_part += (p0 + p1) + (p2 + p3);
                pk[nt].u.x = pk_bf16(p0, p1);
                pk[nt].u.y = pk_bf16(p2, p3);
            }
        }

        __syncthreads();                     // V(t) drained (hidden under QK+softmax)

        // --- O^T += V^T·P^T : A=Vs[d][kv] (k=quad*4+j), B=pk (in registers) ---
#pragma unroll
        for (int kt = 0; kt < 4; kt++) {
#pragma unroll
            for (int dt = 0; dt < 8; dt++) {
                int d = dt * 16 + l16;
                int c = kt * 2 + (quad >> 1);
                s4 va = *(const s4*)&Vs[d * 64 + ((c ^ (d & 7)) * 8) + (quad & 1) * 4];
                ao[dt] = __builtin_amdgcn_mfma_f32_16x16x16bf16_1k(va, pk[kt].s, ao[dt], 0, 0, 0);
            }
        }
    }

    // --- epilogue: reduce l over quads; lane owns q=qg, d=dt*16+quad*4+r ---
    float l = l_part;
    l += __shfl_xor(l, 16);
    l += __shfl_xor(l, 32);
    float inv = 1.0f / l;
    size_t base = ((size_t)b * S_ + qg) * H_ + h * HD_;
#pragma unroll
    for (int dt = 0; dt < 8; dt++) {
        float a0 = ao[dt][0] * inv, a1 = ao[dt][1] * inv;
        float a2 = ao[dt][2] * inv, a3 = ao[dt][3] * inv;
        uint2 st;
        st.x = pk_bf16(a0, a1);
        st.y = pk_bf16(a2, a3);
        *(uint2*)&Ctx[base + dt * 16 + quad * 4] = st;
    }
}

extern "C" void kernel_launch(void* const* d_in, const int* in_sizes, int n_in,
                              void* d_out, int out_size, void* d_ws, size_t ws_size,
                              hipStream_t stream) {
    const float* x  = (const float*)d_in[0];
    const float* Wq = (const float*)d_in[1];
    const float* Wk = (const float*)d_in[2];
    const float* Wv = (const float*)d_in[3];
    const float* Wo = (const float*)d_in[4];
    float* out = (float*)d_out;

    const size_t MB = 1024 * 1024;
    char* ws = (char*)d_ws;
    u16* Xb    = (u16*)(ws);            // 16 MB : x bf16 [4096,2048]
    u16* WqkvT = (u16*)(ws + 16 * MB);  // 24 MB : [6144,2048] (Wq^T;Wk^T;Wv^T)
    u16* WoT   = (u16*)(ws + 40 * MB);  //  8 MB
    u16* Qb    = (u16*)(ws + 48 * MB);  // 16 MB : [B,NH,S,HD], pre-scaled by SL2f
    u16* Kbuf  = (u16*)(ws + 64 * MB);  // 16 MB : [B,NH,S,HD]
    u16* VT    = (u16*)(ws + 80 * MB);  // 16 MB : [B,NH,HD,S]
    u16* Ctx   = (u16*)(ws + 96 * MB);  // 16 MB : [4096,2048]

    cast_x_kernel<<<8192, 256, 0, stream>>>(x, Xb);
    transpose_cast_kernel<<<dim3(64, 64, 4), dim3(32, 8), 0, stream>>>(Wq, Wk, Wv, Wo, WqkvT, WoT);
    gemm_bt<0><<<dim3(48, 32), 256, 0, stream>>>(Xb, WqkvT, nullptr, Qb, Kbuf, VT, 4096, 6144, 2048);
    flash_kernel<<<1024, 256, 0, stream>>>(Qb, Kbuf, VT, Ctx);
    gemm_bt<1><<<dim3(16, 32), 256, 0, stream>>>(Ctx, WoT, out, nullptr, nullptr, nullptr, 4096, 2048, 2048);
}

// Round 6
// 330.959 us; speedup vs baseline: 1.0701x; 1.0701x over previous
//
#include <hip/hip_runtime.h>
#include <stdint.h>

typedef unsigned short u16;
typedef __bf16 bf16x8 __attribute__((ext_vector_type(8)));
typedef short s4 __attribute__((ext_vector_type(4)));
typedef float f32x4 __attribute__((ext_vector_type(4)));

#define B_ 2
#define S_ 2048
#define H_ 2048
#define NH_ 16
#define HD_ 128

// softmax scale folded with log2(e): exp(s*scale) == exp2(s*SL2)
#define SL2f (0.08838834764831845f * 1.4426950408889634f)

__device__ __forceinline__ u16 f2bf(float f) {
    uint32_t u = __float_as_uint(f);
    u += 0x7fff + ((u >> 16) & 1);  // round-to-nearest-even
    return (u16)(u >> 16);
}

// pack two f32 -> two bf16 (truncation) in ONE v_perm_b32 (P values in [0,1]; bias tiny)
__device__ __forceinline__ uint32_t pk_bf16(float lo, float hi) {
    return __builtin_amdgcn_perm(__float_as_uint(hi), __float_as_uint(lo), 0x07060302u);
}

// async global->LDS, 16B per lane, LDS dest = wave-uniform base + lane*16
__device__ __forceinline__ void gl_lds16(const u16* g, u16* l) {
    __builtin_amdgcn_global_load_lds(
        (const __attribute__((address_space(1))) void*)g,
        (__attribute__((address_space(3))) void*)l, 16, 0, 0);
}

union U2S4 { uint2 u; s4 s; };

// ---------------- prep: weight transpose+cast (z<4) and x cast (z==4) ----------------
__global__ __launch_bounds__(256) void prep_kernel(
        const float* __restrict__ x,
        const float* __restrict__ w0, const float* __restrict__ w1,
        const float* __restrict__ w2, const float* __restrict__ w3,
        u16* __restrict__ xb, u16* __restrict__ dqkv, u16* __restrict__ dwo) {
    int z = blockIdx.z;
    int tx = threadIdx.x, ty = threadIdx.y;  // 32 x 8
    if (z == 4) {
        // x cast: 4096 blocks x 2048 elems flat
        int tid = ty * 32 + tx;
        size_t base = ((size_t)(blockIdx.y * 64 + blockIdx.x)) * 2048 + tid * 8;
#pragma unroll
        for (int i = 0; i < 2; i++) {
            float4 v = *(const float4*)&x[base + i * 4];
            ushort4 o;
            o.x = f2bf(v.x); o.y = f2bf(v.y); o.z = f2bf(v.z); o.w = f2bf(v.w);
            *(ushort4*)&xb[base + i * 4] = o;
        }
        return;
    }
    const float* src = (z == 0) ? w0 : (z == 1) ? w1 : (z == 2) ? w2 : w3;
    u16* dst = (z < 3) ? (dqkv + (size_t)z * H_ * H_) : dwo;
    __shared__ float tile[32][33];
    int n0 = blockIdx.x * 32, k0 = blockIdx.y * 32;
#pragma unroll
    for (int i = 0; i < 4; i++)
        tile[ty + i * 8][tx] = src[(size_t)(k0 + ty + i * 8) * H_ + n0 + tx];
    __syncthreads();
#pragma unroll
    for (int i = 0; i < 4; i++)
        dst[(size_t)(n0 + ty + i * 8) * H_ + k0 + tx] = f2bf(tile[tx][ty + i * 8]);
}

// ---------------- GEMM: C[M,N] = A[M,K] @ Bt[N,K]^T  (bf16 in, fp32 acc) ----------------
// MODE 0: N=6144 (Q|K|V). Q pre-scaled by SL2f -> Qb[b,h,s,d]; K -> Kbuf[b,h,s,d];
//         V-tiles transposed through LDS -> VT[b,h,d,s] with coalesced b128 stores.
// MODE 1: fp32 row-major output [M,N].
template <int MODE>
__global__ __launch_bounds__(256, 2) void gemm_bt(
        const u16* __restrict__ A, const u16* __restrict__ Bt, float* __restrict__ Cout,
        u16* __restrict__ q, u16* __restrict__ k, u16* __restrict__ v,
        int M, int N, int K) {
    __shared__ u16 sm[2 * 128 * 64];   // As | Bs; reused as 128x128 u16 for V epilogue
    u16* As = sm;
    u16* Bs = sm + 128 * 64;
    int tid = threadIdx.x;
    int w = tid >> 6, lane = tid & 63, quad = lane >> 4, l16 = lane & 15;
    int wm = w >> 1, wn = w & 1;
    int m0 = blockIdx.y * 128, n0 = blockIdx.x * 128;

    f32x4 acc[4][4];
#pragma unroll
    for (int mi = 0; mi < 4; mi++)
#pragma unroll
        for (int ni = 0; ni < 4; ni++)
            acc[mi][ni] = (f32x4){0.f, 0.f, 0.f, 0.f};

    for (int k0 = 0; k0 < K; k0 += 64) {
        const u16* ga = A + (size_t)m0 * K + k0;
        const u16* gb = Bt + (size_t)n0 * K + k0;
#pragma unroll
        for (int j = 0; j < 4; j++) {
            int base = (j * 4 + w) * 64;
            int p = base + lane;
            int row = p >> 3;
            int c = (p & 7) ^ (row & 7);
            gl_lds16(&ga[(size_t)row * K + c * 8], &As[base * 8]);
            gl_lds16(&gb[(size_t)row * K + c * 8], &Bs[base * 8]);
        }
        __syncthreads();
#pragma unroll
        for (int ks = 0; ks < 2; ks++) {
            bf16x8 af[4], bf[4];
#pragma unroll
            for (int mi = 0; mi < 4; mi++) {
                int row = wm * 64 + mi * 16 + l16;
                af[mi] = *(const bf16x8*)&As[row * 64 + (((ks * 4 + quad) ^ (row & 7)) * 8)];
            }
#pragma unroll
            for (int ni = 0; ni < 4; ni++) {
                int row = wn * 64 + ni * 16 + l16;
                bf[ni] = *(const bf16x8*)&Bs[row * 64 + (((ks * 4 + quad) ^ (row & 7)) * 8)];
            }
#pragma unroll
            for (int mi = 0; mi < 4; mi++)
#pragma unroll
                for (int ni = 0; ni < 4; ni++)
                    acc[mi][ni] = __builtin_amdgcn_mfma_f32_16x16x32_bf16(af[mi], bf[ni], acc[mi][ni], 0, 0, 0);
        }
        __syncthreads();
    }

    // epilogue: D layout col = lane&15, row = quad*4 + r (m89-verified)
    if (MODE == 0 && n0 >= 4096) {
        // ---- V tile: bounce through LDS (swizzled) and store VT[b,h,d,s] coalesced ----
#pragma unroll
        for (int mi = 0; mi < 4; mi++) {
#pragma unroll
            for (int ni = 0; ni < 4; ni++) {
                int nl = wn * 64 + ni * 16 + l16;
#pragma unroll
                for (int r = 0; r < 4; r++) {
                    int ml = wm * 64 + mi * 16 + quad * 4 + r;
                    sm[nl * 128 + (((ml >> 3) ^ (nl & 15)) * 8) + (ml & 7)] = f2bf(acc[mi][ni][r]);
                }
            }
        }
        __syncthreads();
        int b = m0 >> 11, s0 = m0 & 2047;
#pragma unroll
        for (int i = 0; i < 8; i++) {
            int cu = tid + i * 256;
            int nl = cu >> 4, mc = cu & 15;
            int4 val = *(const int4*)&sm[nl * 128 + ((mc ^ (nl & 15)) * 8)];
            int ngl = (n0 - 4096) + nl;
            int h = ngl >> 7, d = ngl & 127;
            *(int4*)&v[((size_t)((b * NH_ + h) * HD_ + d)) * S_ + s0 + mc * 8] = val;
        }
    } else {
#pragma unroll
        for (int mi = 0; mi < 4; mi++) {
#pragma unroll
            for (int ni = 0; ni < 4; ni++) {
                int ng = n0 + wn * 64 + ni * 16 + l16;
#pragma unroll
                for (int r = 0; r < 4; r++) {
                    int mg = m0 + wm * 64 + mi * 16 + quad * 4 + r;
                    float val = acc[mi][ni][r];
                    if (MODE == 0) {
                        int which = ng >> 11;          // 0=Q 1=K
                        int rem = ng & 2047;
                        int h = rem >> 7, d = rem & 127;
                        int b = mg >> 11, s = mg & 2047;
                        if (which == 0)
                            q[((size_t)((b * NH_ + h) * S_ + s)) * HD_ + d] = f2bf(val * SL2f);
                        else
                            k[((size_t)((b * NH_ + h) * S_ + s)) * HD_ + d] = f2bf(val);
                    } else {
                        Cout[(size_t)mg * N + ng] = val;
                    }
                }
            }
        }
    }
}

// ---------------- causal flash attention ----------------
// Paired q-tiles: 512 blocks, block (b,h,pair) does qt=pair then qt=31-pair -> uniform 33 iters.
// S^T = K·Q^T trick: P stays in registers (C-layout == B-frag of 16x16x16 MFMA).
// Barrier plan: phase1 = QK only (mid barrier drains lgkm only); K(t+1),V(t+1) DMA issued
// AFTER mid barrier, hidden under softmax+PV, drained at next top barrier. K,V both dbuf.
// LDS = 2*16K + 2*16K = 64KB -> exactly 2 blocks/CU for the 512-block grid.
__global__ __launch_bounds__(256, 2) void flash_kernel(
        const u16* __restrict__ Q, const u16* __restrict__ Kb,
        const u16* __restrict__ VT, u16* __restrict__ Ctx) {
    __shared__ u16 Ks[2][64 * 128];  // [kv][d], chunk c at c ^ (kv&15)
    __shared__ u16 Vs[2][128 * 64];  // [d][kv], chunk c at c ^ (d&7)
    int tid = threadIdx.x;
    int w = tid >> 6, lane = tid & 63, quad = lane >> 4, l16 = lane & 15;

    int id = blockIdx.x;
    int bh = id & 31;
    int b = bh >> 4, h = bh & 15;
    int pair = id >> 5;              // 0..15
    int qts = pair, qtl = 31 - pair;
    int n0 = qts + 1;                // iters in segment 0; total always 33

    size_t bhoff = ((size_t)b * NH_ + h) * S_ * HD_;
    const u16* Qp = Q + bhoff;
    const u16* Kp = Kb + bhoff;
    const u16* Vp = VT + bhoff;      // [d][s]

    auto stageK = [&](int t, int buf) {
        int kv0 = ((t >= n0) ? (t - n0) : t) * 64;
#pragma unroll
        for (int j = 0; j < 4; j++) {
            int base = (j * 4 + w) * 64;
            int p = base + lane;
            int row = p >> 4;
            int c = (p & 15) ^ (row & 15);
            gl_lds16(&Kp[(size_t)(kv0 + row) * HD_ + c * 8], &Ks[buf][base * 8]);
        }
    };
    auto stageV = [&](int t, int buf) {
        int kv0 = ((t >= n0) ? (t - n0) : t) * 64;
#pragma unroll
        for (int j = 0; j < 4; j++) {
            int base = (j * 4 + w) * 64;
            int p = base + lane;
            int row = p >> 3;
            int c = (p & 7) ^ (row & 7);
            gl_lds16(&Vp[(size_t)row * S_ + kv0 + c * 8], &Vs[buf][base * 8]);
        }
    };

    int q0 = qts * 64;
    int qg = q0 + w * 16 + l16;      // this lane's q row (S^T: lane = q column)
    bf16x8 qf[4];
#pragma unroll
    for (int ks = 0; ks < 4; ks++)
        qf[ks] = *(const bf16x8*)&Qp[(size_t)qg * HD_ + ks * 32 + quad * 8];

    float l_part = 0.f;
    f32x4 ao[8];                     // O^T acc: rows d=dt*16+quad*4+r, col q=l16
#pragma unroll
    for (int dt = 0; dt < 8; dt++) ao[dt] = (f32x4){0.f, 0.f, 0.f, 0.f};

    auto epilogue = [&]() {
        float l = l_part;
        l += __shfl_xor(l, 16);
        l += __shfl_xor(l, 32);
        float inv = 1.0f / l;
        size_t base = ((size_t)b * S_ + qg) * H_ + h * HD_;
#pragma unroll
        for (int dt = 0; dt < 8; dt++) {
            u16 o0 = f2bf(ao[dt][0] * inv), o1 = f2bf(ao[dt][1] * inv);
            u16 o2 = f2bf(ao[dt][2] * inv), o3 = f2bf(ao[dt][3] * inv);
            uint2 st;
            st.x = (uint32_t)o0 | ((uint32_t)o1 << 16);
            st.y = (uint32_t)o2 | ((uint32_t)o3 << 16);
            *(uint2*)&Ctx[base + dt * 16 + quad * 4] = st;
        }
    };

    stageK(0, 0);
    stageV(0, 0);

    for (int t = 0; t < 33; t++) {
        if (t == n0) {               // segment switch (PV of seg0 finished last iter)
            epilogue();
            q0 = qtl * 64;
            qg = q0 + w * 16 + l16;
#pragma unroll
            for (int ks = 0; ks < 4; ks++)
                qf[ks] = *(const bf16x8*)&Qp[(size_t)qg * HD_ + ks * 32 + quad * 8];
            l_part = 0.f;
#pragma unroll
            for (int dt = 0; dt < 8; dt++) ao[dt] = (f32x4){0.f, 0.f, 0.f, 0.f};
        }
        int buf = t & 1;
        __syncthreads();             // A: drains K(t),V(t) DMA (issued last phase-2)

        // --- phase 1: S^T = K·Q^T only (no vmem issued -> cheap mid barrier) ---
        f32x4 sc[4];
#pragma unroll
        for (int nt = 0; nt < 4; nt++) {
            sc[nt] = (f32x4){0.f, 0.f, 0.f, 0.f};
            int row = nt * 16 + l16;
#pragma unroll
            for (int ks = 0; ks < 4; ks++) {
                bf16x8 kf = *(const bf16x8*)&Ks[buf][row * 128 + (((ks * 4 + quad) ^ (row & 15)) * 8)];
                sc[nt] = __builtin_amdgcn_mfma_f32_16x16x32_bf16(kf, qf[ks], sc[nt], 0, 0, 0);
            }
        }

        __syncthreads();             // B: lgkm-only drain

        // --- phase 2: prefetch next K,V (hidden under softmax+PV, drained at next A) ---
        if (t + 1 < 33) {
            stageK(t + 1, buf ^ 1);
            stageV(t + 1, buf ^ 1);
        }

        // --- softmax in registers; pack P^T as 16x16x16 B-fragments ---
        bool diag = (t == n0 - 1) || (t == 32);
        U2S4 pk[4];
        if (!diag) {
#pragma unroll
            for (int nt = 0; nt < 4; nt++) {
                float p0 = exp2f(sc[nt][0]), p1 = exp2f(sc[nt][1]);
                float p2 = exp2f(sc[nt][2]), p3 = exp2f(sc[nt][3]);
                l_part += (p0 + p1) + (p2 + p3);
                pk[nt].u.x = pk_bf16(p0, p1);
                pk[nt].u.y = pk_bf16(p2, p3);
            }
        } else {                     // diagonal tile: causal mask (kv index vs qg)
            int kvb = q0 + quad * 4; // diag tile: kv0 == q0
#pragma unroll
            for (int nt = 0; nt < 4; nt++) {
                int kv = kvb + nt * 16;
                float p0 = (kv + 0 > qg) ? 0.f : exp2f(sc[nt][0]);
                float p1 = (kv + 1 > qg) ? 0.f : exp2f(sc[nt][1]);
                float p2 = (kv + 2 > qg) ? 0.f : exp2f(sc[nt][2]);
                float p3 = (kv + 3 > qg) ? 0.f : exp2f(sc[nt][3]);
                l_part += (p0 + p1) + (p2 + p3);
                pk[nt].u.x = pk_bf16(p0, p1);
                pk[nt].u.y = pk_bf16(p2, p3);
            }
        }

        // --- O^T += V^T·P^T : A=Vs[d][kv], B=pk (registers) ---
#pragma unroll
        for (int kt = 0; kt < 4; kt++) {
#pragma unroll
            for (int dt = 0; dt < 8; dt++) {
                int d = dt * 16 + l16;
                int c = kt * 2 + (quad >> 1);
                s4 va = *(const s4*)&Vs[buf][d * 64 + ((c ^ (d & 7)) * 8) + (quad & 1) * 4];
                ao[dt] = __builtin_amdgcn_mfma_f32_16x16x16bf16_1k(va, pk[kt].s, ao[dt], 0, 0, 0);
            }
        }
    }
    epilogue();
}

extern "C" void kernel_launch(void* const* d_in, const int* in_sizes, int n_in,
                              void* d_out, int out_size, void* d_ws, size_t ws_size,
                              hipStream_t stream) {
    const float* x  = (const float*)d_in[0];
    const float* Wq = (const float*)d_in[1];
    const float* Wk = (const float*)d_in[2];
    const float* Wv = (const float*)d_in[3];
    const float* Wo = (const float*)d_in[4];
    float* out = (float*)d_out;

    const size_t MB = 1024 * 1024;
    char* ws = (char*)d_ws;
    u16* Xb    = (u16*)(ws);            // 16 MB : x bf16 [4096,2048]
    u16* WqkvT = (u16*)(ws + 16 * MB);  // 24 MB : [6144,2048] (Wq^T;Wk^T;Wv^T)
    u16* WoT   = (u16*)(ws + 40 * MB);  //  8 MB
    u16* Qb    = (u16*)(ws + 48 * MB);  // 16 MB : [B,NH,S,HD], pre-scaled by SL2f
    u16* Kbuf  = (u16*)(ws + 64 * MB);  // 16 MB : [B,NH,S,HD]
    u16* VT    = (u16*)(ws + 80 * MB);  // 16 MB : [B,NH,HD,S]
    u16* Ctx   = (u16*)(ws + 96 * MB);  // 16 MB : [4096,2048]

    prep_kernel<<<dim3(64, 64, 5), dim3(32, 8), 0, stream>>>(x, Wq, Wk, Wv, Wo, Xb, WqkvT, WoT);
    gemm_bt<0><<<dim3(48, 32), 256, 0, stream>>>(Xb, WqkvT, nullptr, Qb, Kbuf, VT, 4096, 6144, 2048);
    flash_kernel<<<512, 256, 0, stream>>>(Qb, Kbuf, VT, Ctx);
    gemm_bt<1><<<dim3(16, 32), 256, 0, stream>>>(Ctx, WoT, out, nullptr, nullptr, nullptr, 4096, 2048, 2048);
}